// Round 5
// baseline (212.444 us; speedup 1.0000x reference)
//
#include <hip/hip_runtime.h>
#include <math.h>

// x, x_r: (1, 3, 32, 512, 512) fp32. size=64 -> hc=wc=32, nh=nw=16.
// P[t,ph,pw] = mean over (c=3, 32x32) of |x - x_r|/2   (3072 elems/patch)
// out = log( mean_t( max(0, max_{ph,pw} P) ) )  -- scalar fp32.
//
// Round 5: streaming structure (copy-benchmark style).
//   Chunk = contiguous 2048 f4 (16 rows x 512 cols of one (ch,t) frame).
//   3072 chunks total. 1024 blocks x 256 thr; block b streams chunks
//   3b, 3b+1, 3b+2 (96 KB contiguous span per input): 48 independent
//   float4 loads per thread in one long run -> continuous MLP, no
//   per-block burst/drain. Per-chunk pw bin = (tid&127)>>3 is constant
//   per thread -> 3 scalar accumulators; single LDS phase at the end.
// Kernel 2: one 1024-thread block: sum 6 chunk-contributions per patch,
//   per-t max, clamp, mean, log (unchanged, measured fast).

__global__ __launch_bounds__(256) void patch_sum_kernel(
    const float* __restrict__ x, const float* __restrict__ xr,
    float* __restrict__ part) {
  const int b   = blockIdx.x;        // 0..1023
  const int tid = threadIdx.x;
  const size_t base4 = (size_t)b * 3 * 2048;
  const float4* __restrict__ a4 = (const float4*)x  + base4;
  const float4* __restrict__ c4 = (const float4*)xr + base4;

  float acc0 = 0.f, acc1 = 0.f, acc2 = 0.f;
#pragma unroll
  for (int i = 0; i < 8; ++i) {
    int o = i * 256 + tid;
    {
      float4 a = a4[o];
      float4 c = c4[o];
      acc0 += fabsf(a.x - c.x) + fabsf(a.y - c.y)
            + fabsf(a.z - c.z) + fabsf(a.w - c.w);
    }
    {
      float4 a = a4[2048 + o];
      float4 c = c4[2048 + o];
      acc1 += fabsf(a.x - c.x) + fabsf(a.y - c.y)
            + fabsf(a.z - c.z) + fabsf(a.w - c.w);
    }
    {
      float4 a = a4[4096 + o];
      float4 c = c4[4096 + o];
      acc2 += fabsf(a.x - c.x) + fabsf(a.y - c.y)
            + fabsf(a.z - c.z) + fabsf(a.w - c.w);
    }
  }

  // 8-lane group reduce for each chunk accumulator (bin = (tid&127)>>3).
#pragma unroll
  for (int o = 4; o > 0; o >>= 1) {
    acc0 += __shfl_down(acc0, o, 8);
    acc1 += __shfl_down(acc1, o, 8);
    acc2 += __shfl_down(acc2, o, 8);
  }
  __shared__ float s[3][32];
  if ((tid & 7) == 0) {
    int m = tid >> 3;                // 0..31 ; bin = m & 15
    s[0][m] = acc0;
    s[1][m] = acc1;
    s[2][m] = acc2;
  }
  __syncthreads();
  if (tid < 48) {
    int k = tid >> 4;                // which chunk of the 3
    int bin = tid & 15;              // pw
    float v = s[k][bin] + s[k][bin + 16];
    part[(size_t)(b * 3 + k) * 16 + bin] = v;
  }
}

__global__ __launch_bounds__(1024) void finalize_kernel(
    const float* __restrict__ part, float* __restrict__ out) {
  const int tid = threadIdx.x;
  const int t = tid >> 5;             // 0..31
  const int j = tid & 31;
  float m = -1e30f;
#pragma unroll
  for (int k = 0; k < 8; ++k) {
    int p = t * 256 + j + 32 * k;     // patch id within frame t
    int ph = (p >> 4) & 15;
    int pw = p & 15;
    float v = 0.f;
#pragma unroll
    for (int ch = 0; ch < 3; ++ch) {
#pragma unroll
      for (int half = 0; half < 2; ++half) {
        int idx = ((ch << 10) + (t << 5) + (ph << 1) + half) * 16 + pw;
        v += part[idx];
      }
    }
    m = fmaxf(m, v);
  }
#pragma unroll
  for (int o = 16; o > 0; o >>= 1) m = fmaxf(m, __shfl_down(m, o, 32));
  __shared__ float s[32];
  if (j == 0) s[t] = fmaxf(m * (0.5f / 3072.0f), 0.f);  // scale + clamp at 0
  __syncthreads();
  if (tid < 32) {
    float v = s[tid];
#pragma unroll
    for (int o = 16; o > 0; o >>= 1) v += __shfl_down(v, o, 32);
    if (tid == 0) out[0] = logf(v * (1.0f / 32.0f));
  }
}

extern "C" void kernel_launch(void* const* d_in, const int* in_sizes, int n_in,
                              void* d_out, int out_size, void* d_ws, size_t ws_size,
                              hipStream_t stream) {
  const float* x  = (const float*)d_in[0];
  const float* xr = (const float*)d_in[1];
  float* part = (float*)d_ws;        // 3072*16 floats = 192 KB scratch
  float* out  = (float*)d_out;

  patch_sum_kernel<<<1024, 256, 0, stream>>>(x, xr, part);
  finalize_kernel<<<1, 1024, 0, stream>>>(part, out);
}

// Round 7
// 194.209 us; speedup vs baseline: 1.0939x; 1.0939x over previous
//
#include <hip/hip_runtime.h>
#include <math.h>

// x, x_r: (1, 3, 32, 512, 512) fp32. size=64 -> hc=wc=32, nh=nw=16.
// P[t,ph,pw] = mean over (c=3, 32x32) of |x - x_r|/2   (3072 elems/patch)
// out = log( mean_t( max(0, max_{ph,pw} P) ) )  -- scalar fp32.
//
// Round 7 (= round 6 with compile fix): NON-TEMPORAL loads (nt -> no L1
//   allocate). Theory: the invariant ~2.8 TB/s read rate across 5 structural
//   variants is a per-CU L1/TCP miss-slot cap (~32 x 128 B lines / ~900 cyc
//   = 4.5 B/cyc/CU). nt loads stream past L1, possibly deeper queue.
//   __builtin_nontemporal_load needs a native vector type, not
//   HIP_vector_type -> use clang ext_vector float4.
//   Geometry = round 4: 3072 blocks x 256 thr; block b = contiguous 2048-f4
//   chunk (16 rows x 512 cols); f4 idx = i*256+tid -> pw bin = (tid&127)>>3
//   constant per thread -> scalar accumulator.
// Kernel 2: one 1024-thread block: sum 6 chunk-contributions per patch,
//   per-t max, clamp, mean, log (unchanged, measured fast).

typedef float vf4 __attribute__((ext_vector_type(4)));

__global__ __launch_bounds__(256) void patch_sum_kernel(
    const float* __restrict__ x, const float* __restrict__ xr,
    float* __restrict__ part) {
  const int b   = blockIdx.x;        // 0..3071, chunk = contiguous 2048 f4
  const int tid = threadIdx.x;
  const vf4* __restrict__ a4 = (const vf4*)x  + (size_t)b * 2048;
  const vf4* __restrict__ c4 = (const vf4*)xr + (size_t)b * 2048;

  float s0 = 0.f, s1 = 0.f, s2 = 0.f, s3 = 0.f;
#pragma unroll
  for (int i = 0; i < 8; ++i) {
    vf4 a = __builtin_nontemporal_load(&a4[i * 256 + tid]);
    vf4 c = __builtin_nontemporal_load(&c4[i * 256 + tid]);
    s0 += fabsf(a.x - c.x);
    s1 += fabsf(a.y - c.y);
    s2 += fabsf(a.z - c.z);
    s3 += fabsf(a.w - c.w);
  }
  float acc = (s0 + s1) + (s2 + s3);

  // 16 pw bins; thread bin = (tid&127)>>3. Reduce 8 consecutive lanes, then
  // 32 leaders (m = tid>>3) land in LDS; bin = m&15; combine pairs.
  acc += __shfl_down(acc, 4, 8);
  acc += __shfl_down(acc, 2, 8);
  acc += __shfl_down(acc, 1, 8);
  __shared__ float s[32];
  if ((tid & 7) == 0) s[tid >> 3] = acc;
  __syncthreads();
  // part[b*16 + pw]; b = ch*1024 + t*32 + ph*2 + half
  if (tid < 16) part[(size_t)b * 16 + tid] = s[tid] + s[tid + 16];
}

__global__ __launch_bounds__(1024) void finalize_kernel(
    const float* __restrict__ part, float* __restrict__ out) {
  const int tid = threadIdx.x;
  const int t = tid >> 5;             // 0..31
  const int j = tid & 31;
  float m = -1e30f;
#pragma unroll
  for (int k = 0; k < 8; ++k) {
    int p = t * 256 + j + 32 * k;     // patch id within frame t
    int ph = (p >> 4) & 15;
    int pw = p & 15;
    float v = 0.f;
#pragma unroll
    for (int ch = 0; ch < 3; ++ch) {
#pragma unroll
      for (int half = 0; half < 2; ++half) {
        int idx = ((ch << 10) + (t << 5) + (ph << 1) + half) * 16 + pw;
        v += part[idx];
      }
    }
    m = fmaxf(m, v);
  }
#pragma unroll
  for (int o = 16; o > 0; o >>= 1) m = fmaxf(m, __shfl_down(m, o, 32));
  __shared__ float s[32];
  if (j == 0) s[t] = fmaxf(m * (0.5f / 3072.0f), 0.f);  // scale + clamp at 0
  __syncthreads();
  if (tid < 32) {
    float v = s[tid];
#pragma unroll
    for (int o = 16; o > 0; o >>= 1) v += __shfl_down(v, o, 32);
    if (tid == 0) out[0] = logf(v * (1.0f / 32.0f));
  }
}

extern "C" void kernel_launch(void* const* d_in, const int* in_sizes, int n_in,
                              void* d_out, int out_size, void* d_ws, size_t ws_size,
                              hipStream_t stream) {
  const float* x  = (const float*)d_in[0];
  const float* xr = (const float*)d_in[1];
  float* part = (float*)d_ws;        // 3072*16 floats = 192 KB scratch
  float* out  = (float*)d_out;

  patch_sum_kernel<<<3072, 256, 0, stream>>>(x, xr, part);
  finalize_kernel<<<1, 1024, 0, stream>>>(part, out);
}

// Round 8
// 194.001 us; speedup vs baseline: 1.0951x; 1.0011x over previous
//
#include <hip/hip_runtime.h>
#include <math.h>

// x, x_r: (1, 3, 32, 512, 512) fp32. size=64 -> hc=wc=32, nh=nw=16.
// P[t,ph,pw] = mean over (c=3, 32x32) of |x - x_r|/2   (3072 elems/patch)
// out = log( mean_t( max(0, max_{ph,pw} P) ) )  -- scalar fp32.
//
// Round 8: nt loads (worked: 72 -> <58 us, L1 miss-slot cap bypassed)
//   + round-5 streaming structure for MLP now that L1 is out of the path.
//   Chunk = contiguous 2048 f4 (16 rows x 512 cols of one (ch,t) frame);
//   3072 chunks. 1024 blocks x 256 thr; block b streams chunks 3b..3b+2
//   (96 KB contiguous per input): each inner iter issues 6 independent nt
//   loads into 3 independent accumulators -> continuous issue, no drain.
//   pw bin = (tid&127)>>3 constant per thread -> scalar accumulators.
// Kernel 2: one 1024-thread block: sum 6 chunk-contributions per patch,
//   per-t max, clamp, mean, log (unchanged, measured fast).

typedef float vf4 __attribute__((ext_vector_type(4)));

__global__ __launch_bounds__(256) void patch_sum_kernel(
    const float* __restrict__ x, const float* __restrict__ xr,
    float* __restrict__ part) {
  const int b   = blockIdx.x;        // 0..1023
  const int tid = threadIdx.x;
  const size_t base4 = (size_t)b * 3 * 2048;
  const vf4* __restrict__ a4 = (const vf4*)x  + base4;
  const vf4* __restrict__ c4 = (const vf4*)xr + base4;

  float acc0 = 0.f, acc1 = 0.f, acc2 = 0.f;
#pragma unroll
  for (int i = 0; i < 8; ++i) {
    int o = i * 256 + tid;
    vf4 a0 = __builtin_nontemporal_load(&a4[o]);
    vf4 c0 = __builtin_nontemporal_load(&c4[o]);
    vf4 a1 = __builtin_nontemporal_load(&a4[2048 + o]);
    vf4 c1 = __builtin_nontemporal_load(&c4[2048 + o]);
    vf4 a2 = __builtin_nontemporal_load(&a4[4096 + o]);
    vf4 c2 = __builtin_nontemporal_load(&c4[4096 + o]);
    acc0 += fabsf(a0.x - c0.x) + fabsf(a0.y - c0.y)
          + fabsf(a0.z - c0.z) + fabsf(a0.w - c0.w);
    acc1 += fabsf(a1.x - c1.x) + fabsf(a1.y - c1.y)
          + fabsf(a1.z - c1.z) + fabsf(a1.w - c1.w);
    acc2 += fabsf(a2.x - c2.x) + fabsf(a2.y - c2.y)
          + fabsf(a2.z - c2.z) + fabsf(a2.w - c2.w);
  }

  // 8-lane group reduce for each chunk accumulator (bin = (tid&127)>>3).
#pragma unroll
  for (int o = 4; o > 0; o >>= 1) {
    acc0 += __shfl_down(acc0, o, 8);
    acc1 += __shfl_down(acc1, o, 8);
    acc2 += __shfl_down(acc2, o, 8);
  }
  __shared__ float s[3][32];
  if ((tid & 7) == 0) {
    int m = tid >> 3;                // 0..31 ; bin = m & 15
    s[0][m] = acc0;
    s[1][m] = acc1;
    s[2][m] = acc2;
  }
  __syncthreads();
  if (tid < 48) {
    int k = tid >> 4;                // which chunk of the 3
    int bin = tid & 15;              // pw
    part[(size_t)(b * 3 + k) * 16 + bin] = s[k][bin] + s[k][bin + 16];
  }
}

__global__ __launch_bounds__(1024) void finalize_kernel(
    const float* __restrict__ part, float* __restrict__ out) {
  const int tid = threadIdx.x;
  const int t = tid >> 5;             // 0..31
  const int j = tid & 31;
  float m = -1e30f;
#pragma unroll
  for (int k = 0; k < 8; ++k) {
    int p = t * 256 + j + 32 * k;     // patch id within frame t
    int ph = (p >> 4) & 15;
    int pw = p & 15;
    float v = 0.f;
#pragma unroll
    for (int ch = 0; ch < 3; ++ch) {
#pragma unroll
      for (int half = 0; half < 2; ++half) {
        int idx = ((ch << 10) + (t << 5) + (ph << 1) + half) * 16 + pw;
        v += part[idx];
      }
    }
    m = fmaxf(m, v);
  }
#pragma unroll
  for (int o = 16; o > 0; o >>= 1) m = fmaxf(m, __shfl_down(m, o, 32));
  __shared__ float s[32];
  if (j == 0) s[t] = fmaxf(m * (0.5f / 3072.0f), 0.f);  // scale + clamp at 0
  __syncthreads();
  if (tid < 32) {
    float v = s[tid];
#pragma unroll
    for (int o = 16; o > 0; o >>= 1) v += __shfl_down(v, o, 32);
    if (tid == 0) out[0] = logf(v * (1.0f / 32.0f));
  }
}

extern "C" void kernel_launch(void* const* d_in, const int* in_sizes, int n_in,
                              void* d_out, int out_size, void* d_ws, size_t ws_size,
                              hipStream_t stream) {
  const float* x  = (const float*)d_in[0];
  const float* xr = (const float*)d_in[1];
  float* part = (float*)d_ws;        // 3072*16 floats = 192 KB scratch
  float* out  = (float*)d_out;

  patch_sum_kernel<<<1024, 256, 0, stream>>>(x, xr, part);
  finalize_kernel<<<1, 1024, 0, stream>>>(part, out);
}